// Round 3
// 899.448 us; speedup vs baseline: 1.0932x; 1.0932x over previous
//
#include <hip/hip_runtime.h>
#include <hip/hip_fp16.h>
#include <cstdint>
#include <cstddef>

// Problem constants
constexpr int HD   = 512;          // hidden
constexpr int SQ   = 512;          // seq len
constexpr int NB   = 32;           // batch
constexpr int LAY  = 3;            // layers
constexpr int WID  = 4;            // conv width
constexpr int KIN  = (WID + 1) * HD;   // 2560
constexpr int PROW = SQ + 2 * WID;     // 520 padded rows
constexpr int MR   = NB * SQ;          // 16384 GEMM rows
constexpr int PSTR = NB * PROW * HD;   // pad buffer stride (elems)

typedef _Float16 f16x8 __attribute__((ext_vector_type(8)));
typedef float    f32x4 __attribute__((ext_vector_type(4)));

#define VMCNT(n) asm volatile("s_waitcnt vmcnt(" #n ")" ::: "memory")
#define LGKM0()  asm volatile("s_waitcnt lgkmcnt(0)" ::: "memory")
#define SBAR()   asm volatile("s_barrier" ::: "memory")

__device__ __forceinline__ void gld16(void* lds, const void* g) {
  __builtin_amdgcn_global_load_lds(
      (__attribute__((address_space(1))) void*)(g),
      (__attribute__((address_space(3))) void*)(lds),
      16, 0, 0);
}

// Stage one 256x32 f16 region (16 KB) with 512 threads: 2 x gld16 each.
// LDS layout is linear in (row, physchunk); swizzle is applied by inverse-
// permuting the GLOBAL source chunk: q = phys ^ ((row>>1)&3).  (both-sides rule)
__device__ __forceinline__ void stage_reg(_Float16* dst, const _Float16* src0,
                                          int rstride, int tid) {
#pragma unroll
  for (int j = 0; j < 2; ++j) {
    const int l = j * 512 + tid;
    const int r = l >> 2;
    const int c = ((l & 3) ^ ((r >> 1) & 3)) << 3;   // logical k-chunk * 8
    gld16(dst + (size_t)l * 8, src0 + (size_t)r * rstride + c);
  }
}

// Read one f16x8 MFMA fragment from a 256x32 region (swizzled).
__device__ __forceinline__ f16x8 rdfrag(const _Float16* reg, int row, int q) {
  return *(const f16x8*)&reg[row * 32 + ((q ^ ((row >> 1) & 3)) << 3)];
}

// ---------------------------------------------------------------------------
// Paired weight transpose+convert: fp32 [nsl][R][C] x2 -> fp16 [nsl][C][R] x2
// ilv=1: pair-interleave output rows (row 2j = col j, row 2j+1 = col half+j)
// so highway (nonlin, gate) columns land adjacent.
// ---------------------------------------------------------------------------
__global__ void transpose_w2(const float* __restrict__ inF, const float* __restrict__ inB,
                             _Float16* __restrict__ outF, _Float16* __restrict__ outB,
                             int R, int C, int nsl, int ilv) {
  __shared__ float tile[32][33];
  const int z = blockIdx.z;
  const float* in = (z < nsl) ? inF : inB;
  _Float16* out   = (z < nsl) ? outF : outB;
  const int sl    = (z < nsl) ? z : z - nsl;
  const size_t base = (size_t)sl * R * C;
  const int r0 = blockIdx.y * 32, c0 = blockIdx.x * 32;
  const int tx = threadIdx.x, ty = threadIdx.y;  // (32, 8)
  const int half = C >> 1;
#pragma unroll
  for (int j = 0; j < 32; j += 8)
    tile[ty + j][tx] = in[base + (size_t)(r0 + ty + j) * C + (c0 + tx)];
  __syncthreads();
#pragma unroll
  for (int j = 0; j < 32; j += 8) {
    const int c = c0 + ty + j;
    const int cc = ilv ? (((c & (half - 1)) << 1) | (c >= half ? 1 : 0)) : c;
    out[base + (size_t)cc * R + (r0 + tx)] = (_Float16)tile[tx][ty + j];
  }
}

// ---------------------------------------------------------------------------
// Layer-0 interior: inputs fp32 [B][S][H] -> layer-0 pad interiors fp16
// ---------------------------------------------------------------------------
__global__ void init_interior(const float4* __restrict__ in,
                              _Float16* __restrict__ padF, _Float16* __restrict__ padB) {
  const size_t idx = (size_t)blockIdx.x * 256 + threadIdx.x;  // over B*S*H/4
  float4 v = in[idx];
  const size_t e = idx * 4;
  const int h = (int)(e & (HD - 1));
  const size_t bt = e >> 9;
  const int t = (int)(bt & (SQ - 1));
  const int b = (int)(bt >> 9);
  const size_t o = ((size_t)(b * PROW + WID + t)) * HD + h;
  union { _Float16 hh[4]; uint2 u; } pk;
  pk.hh[0] = (_Float16)v.x; pk.hh[1] = (_Float16)v.y;
  pk.hh[2] = (_Float16)v.z; pk.hh[3] = (_Float16)v.w;
  *(uint2*)&padF[o] = pk.u;
  *(uint2*)&padB[o] = pk.u;
}

// ---------------------------------------------------------------------------
// Fill border rows of ALL 3 layers' pad buffers once.
// ---------------------------------------------------------------------------
__global__ void fill_all_pads(const float* __restrict__ fpads, const float* __restrict__ bpads,
                              _Float16* __restrict__ padF, _Float16* __restrict__ padB) {
  const int idx = blockIdx.x * 256 + threadIdx.x;  // 3*2^17 total
  const int h  = idx & (HD - 1);
  const int w  = (idx >> 9) & 3;
  const int b  = (idx >> 11) & 31;
  const int fb = (idx >> 16) & 1;
  const int l  = idx >> 17;
  const float v = fb ? bpads[l * WID * HD + w * HD + h] : fpads[l * WID * HD + w * HD + h];
  const int row = fb ? (SQ + WID + w) : w;
  const size_t o = (size_t)l * PSTR + ((size_t)(b * PROW + row)) * HD + h;
  const _Float16 hv = (_Float16)v;
  padF[o] = hv;
  padB[o] = hv;
}

// ===========================================================================
// 256x256-tile 8-phase conv GEMM.  512 threads = 8 waves (2M x 4N), BK=64.
// STATIC LDS 128 KiB: 2 dbuf x {A-kh0, B-kh0, A-kh1, B-kh1} regions 256x32 f16.
// Stage schedule (region for K-tile kt+2 of buf(kt)):
//   A0 @P1(kt), B0 @P2(kt), A1 @P3(kt), B1 @P0(kt+1)  -> vmcnt(10) at P0/P2.
// Tail issues clamped dummy stages into dead regions to keep vmcnt invariant.
// lgkmcnt(0) before every phase-end barrier: no wave crosses with ds_reads in
// flight (next phase overwrites the region just read).
// grid: 256 blocks (1/CU).
// ===========================================================================
__global__ __launch_bounds__(512, 2)
void conv_gemm(const _Float16* __restrict__ padFp, const _Float16* __restrict__ padBp,
               const _Float16* __restrict__ WtF, const _Float16* __restrict__ WtB,
               const float* __restrict__ biasF, const float* __restrict__ biasB,
               _Float16* __restrict__ tF, _Float16* __restrict__ tB) {
  constexpr int NT = KIN / 64;   // 40
  __shared__ alignas(16) _Float16 LDSA[65536];   // 128 KiB static

  const int id = blockIdx.x;
  const int lg = (id & 7) * 32 + (id >> 3);   // XCD-contiguous
  const int dir = lg >> 7;
  const int nt  = (lg >> 6) & 1;
  const int mt  = lg & 63;

  const _Float16* pad = dir ? padBp : padFp;
  const _Float16* Wt  = dir ? WtB : WtF;
  const float* bias   = dir ? biasB : biasF;
  _Float16* outT      = dir ? tB : tF;
  const int off = dir ? WID : 0;

  const int m0 = mt * 256, n0 = nt * 256;
  const int b  = m0 >> 9, t0 = m0 & (SQ - 1);
  const int arow0 = b * PROW + t0 + off;

  const int tid  = threadIdx.x;
  const int lane = tid & 63, wv = tid >> 6;
  const int wm = wv >> 2, wn = wv & 3;
  const int lr = lane & 15, q = lane >> 4;

  f32x4 acc[8][4] = {};

  auto As = [&](int reg, int kk) {
    const int kseg = kk >> 9, h0 = kk & (HD - 1);
    stage_reg(LDSA + reg * 8192, pad + (size_t)(arow0 + kseg) * HD + h0, HD, tid);
  };
  auto Bs = [&](int reg, int kk) {
    stage_reg(LDSA + reg * 8192, Wt + (size_t)n0 * KIN + kk, KIN, tid);
  };

  // Prologue: kt0 fully (A0,B0,A1,B1 of buf0), kt1 partially (A0,B0,A1 of buf1)
  As(0, 0);  Bs(1, 0);  As(2, 32); Bs(3, 32);
  As(4, 64); Bs(5, 64); As(6, 96);

#pragma unroll 2
  for (int kt = 0; kt < NT; ++kt) {
    const int bf_ = (kt & 1) * 4, of_ = 4 - bf_;
    const _Float16* A0 = LDSA + (bf_ + 0) * 8192;
    const _Float16* B0 = LDSA + (bf_ + 1) * 8192;
    const _Float16* A1 = LDSA + (bf_ + 2) * 8192;
    const _Float16* B1 = LDSA + (bf_ + 3) * 8192;
    const int k1 = (kt + 1 < NT ? kt + 1 : NT - 1) * 64;
    const int k2 = (kt + 2 < NT ? kt + 2 : NT - 1) * 64;

    f16x8 aF[8], bF[2];

    // -------- P0: kh0, nj 0-1 (reads A0 fresh + B0)
    VMCNT(10);
    Bs(of_ + 3, k1 + 32);               // B1[kt+1] into other buf
    SBAR();
#pragma unroll
    for (int mi = 0; mi < 8; ++mi) aF[mi] = rdfrag(A0, wm * 128 + mi * 16 + lr, q);
#pragma unroll
    for (int nj = 0; nj < 2; ++nj) bF[nj] = rdfrag(B0, wn * 64 + nj * 16 + lr, q);
    __builtin_amdgcn_s_setprio(1);
#pragma unroll
    for (int mi = 0; mi < 8; ++mi)
#pragma unroll
      for (int nj = 0; nj < 2; ++nj)
        acc[mi][nj] = __builtin_amdgcn_mfma_f32_16x16x32_f16(aF[mi], bF[nj], acc[mi][nj], 0, 0, 0);
    __builtin_amdgcn_s_setprio(0);
    LGKM0();
    SBAR();

    // -------- P1: kh0, nj 2-3 (reuse aF)
    As(bf_ + 0, k2);                    // A0[kt+2] (A0 dead after P0)
    SBAR();
#pragma unroll
    for (int nj = 0; nj < 2; ++nj) bF[nj] = rdfrag(B0, wn * 64 + (nj + 2) * 16 + lr, q);
    __builtin_amdgcn_s_setprio(1);
#pragma unroll
    for (int mi = 0; mi < 8; ++mi)
#pragma unroll
      for (int nj = 0; nj < 2; ++nj)
        acc[mi][nj + 2] = __builtin_amdgcn_mfma_f32_16x16x32_f16(aF[mi], bF[nj], acc[mi][nj + 2], 0, 0, 0);
    __builtin_amdgcn_s_setprio(0);
    LGKM0();
    SBAR();

    // -------- P2: kh1, nj 0-1
    VMCNT(10);
    Bs(bf_ + 1, k2);                    // B0[kt+2] (B0 dead after P1)
    SBAR();
#pragma unroll
    for (int mi = 0; mi < 8; ++mi) aF[mi] = rdfrag(A1, wm * 128 + mi * 16 + lr, q);
#pragma unroll
    for (int nj = 0; nj < 2; ++nj) bF[nj] = rdfrag(B1, wn * 64 + nj * 16 + lr, q);
    __builtin_amdgcn_s_setprio(1);
#pragma unroll
    for (int mi = 0; mi < 8; ++mi)
#pragma unroll
      for (int nj = 0; nj < 2; ++nj)
        acc[mi][nj] = __builtin_amdgcn_mfma_f32_16x16x32_f16(aF[mi], bF[nj], acc[mi][nj], 0, 0, 0);
    __builtin_amdgcn_s_setprio(0);
    LGKM0();
    SBAR();

    // -------- P3: kh1, nj 2-3 (reuse aF)
    As(bf_ + 2, k2 + 32);               // A1[kt+2] (A1 dead after P2)
    SBAR();
#pragma unroll
    for (int nj = 0; nj < 2; ++nj) bF[nj] = rdfrag(B1, wn * 64 + (nj + 2) * 16 + lr, q);
    __builtin_amdgcn_s_setprio(1);
#pragma unroll
    for (int mi = 0; mi < 8; ++mi)
#pragma unroll
      for (int nj = 0; nj < 2; ++nj)
        acc[mi][nj + 2] = __builtin_amdgcn_mfma_f32_16x16x32_f16(aF[mi], bF[nj], acc[mi][nj + 2], 0, 0, 0);
    __builtin_amdgcn_s_setprio(0);
    LGKM0();
    SBAR();
  }

  // -------- Epilogue: drain all DMAs, then bias+relu -> LDS -> vector stores
  VMCNT(0);
  SBAR();
  _Float16* E = LDSA;  // 256x256 f16 row-major
#pragma unroll
  for (int nj = 0; nj < 4; ++nj) {
    const int col = wn * 64 + nj * 16 + lr;
    const float bv = bias[n0 + col];
#pragma unroll
    for (int mi = 0; mi < 8; ++mi)
#pragma unroll
      for (int g = 0; g < 4; ++g) {
        const int row = wm * 128 + mi * 16 + q * 4 + g;
        float v = acc[mi][nj][g] + bv;
        v = v > 0.f ? v : 0.f;
        E[row * 256 + col] = (_Float16)v;
      }
  }
  LGKM0();
  SBAR();
  // 256x256 f16 = 8192 16B-chunks; 512 threads -> 16 iterations (was 8: BUG,
  // rows 128..255 were never stored).
#pragma unroll
  for (int j = 0; j < 16; ++j) {
    const int cid = j * 512 + tid;
    const int row = cid >> 5, c = cid & 31;
    f16x8 v8 = *(const f16x8*)&E[row * 256 + c * 8];
    *(f16x8*)&outT[(size_t)(m0 + row) * HD + n0 + c * 8] = v8;
  }
}

// ===========================================================================
// 256x256-tile 8-phase highway GEMM.  Weights pre-interleaved: row 2j=nonlin,
// row 2j+1=gate -> standard GEMM, block covers 128 (nonlin,gate) output pairs.
// mode 0: fp16 oh [16384][512]. mode 1: fp16 into next layer's pad interior
// AND fp32 out32. mode 2: fp32 out32 only.
// grid: 512 blocks.
// ===========================================================================
__global__ __launch_bounds__(512, 2)
void hw_gemm(const _Float16* __restrict__ xF, const _Float16* __restrict__ xB,
             const _Float16* __restrict__ WtFp, const _Float16* __restrict__ WtBp,
             const float* __restrict__ bFp, const float* __restrict__ bBp,
             _Float16* __restrict__ oFp, _Float16* __restrict__ oBp,
             float* __restrict__ out32, int mode) {
  constexpr int NT = HD / 64;   // 8
  __shared__ alignas(16) _Float16 LDSA[65536];   // 128 KiB static

  const int id = blockIdx.x;
  const int lg = (id & 7) * 64 + (id >> 3);   // XCD-contiguous
  const int dir = lg >> 8;
  const int r2  = lg & 255;
  const int nt  = r2 >> 6, mt = r2 & 63;

  const _Float16* x  = dir ? xB : xF;
  const _Float16* Wt = dir ? WtBp : WtFp;
  const float* bias  = dir ? bBp : bFp;
  _Float16* oh       = dir ? oBp : oFp;

  const int m0 = mt * 256, n0 = nt * 256;

  const int tid  = threadIdx.x;
  const int lane = tid & 63, wv = tid >> 6;
  const int wm = wv >> 2, wn = wv & 3;
  const int lr = lane & 15, q = lane >> 4;

  f32x4 acc[8][4] = {};

  auto As = [&](int reg, int kk) {
    stage_reg(LDSA + reg * 8192, x + (size_t)m0 * HD + kk, HD, tid);
  };
  auto Bs = [&](int reg, int kk) {
    stage_reg(LDSA + reg * 8192, Wt + (size_t)n0 * HD + kk, HD, tid);
  };

  As(0, 0);  Bs(1, 0);  As(2, 32); Bs(3, 32);
  As(4, 64); Bs(5, 64); As(6, 96);

#pragma unroll 2
  for (int kt = 0; kt < NT; ++kt) {
    const int bf_ = (kt & 1) * 4, of_ = 4 - bf_;
    const _Float16* A0 = LDSA + (bf_ + 0) * 8192;
    const _Float16* B0 = LDSA + (bf_ + 1) * 8192;
    const _Float16* A1 = LDSA + (bf_ + 2) * 8192;
    const _Float16* B1 = LDSA + (bf_ + 3) * 8192;
    const int k1 = (kt + 1 < NT ? kt + 1 : NT - 1) * 64;
    const int k2 = (kt + 2 < NT ? kt + 2 : NT - 1) * 64;

    f16x8 aF[8], bF[2];

    // P0
    VMCNT(10);
    Bs(of_ + 3, k1 + 32);
    SBAR();
#pragma unroll
    for (int mi = 0; mi < 8; ++mi) aF[mi] = rdfrag(A0, wm * 128 + mi * 16 + lr, q);
#pragma unroll
    for (int nj = 0; nj < 2; ++nj) bF[nj] = rdfrag(B0, wn * 64 + nj * 16 + lr, q);
    __builtin_amdgcn_s_setprio(1);
#pragma unroll
    for (int mi = 0; mi < 8; ++mi)
#pragma unroll
      for (int nj = 0; nj < 2; ++nj)
        acc[mi][nj] = __builtin_amdgcn_mfma_f32_16x16x32_f16(aF[mi], bF[nj], acc[mi][nj], 0, 0, 0);
    __builtin_amdgcn_s_setprio(0);
    LGKM0();
    SBAR();

    // P1
    As(bf_ + 0, k2);
    SBAR();
#pragma unroll
    for (int nj = 0; nj < 2; ++nj) bF[nj] = rdfrag(B0, wn * 64 + (nj + 2) * 16 + lr, q);
    __builtin_amdgcn_s_setprio(1);
#pragma unroll
    for (int mi = 0; mi < 8; ++mi)
#pragma unroll
      for (int nj = 0; nj < 2; ++nj)
        acc[mi][nj + 2] = __builtin_amdgcn_mfma_f32_16x16x32_f16(aF[mi], bF[nj], acc[mi][nj + 2], 0, 0, 0);
    __builtin_amdgcn_s_setprio(0);
    LGKM0();
    SBAR();

    // P2
    VMCNT(10);
    Bs(bf_ + 1, k2);
    SBAR();
#pragma unroll
    for (int mi = 0; mi < 8; ++mi) aF[mi] = rdfrag(A1, wm * 128 + mi * 16 + lr, q);
#pragma unroll
    for (int nj = 0; nj < 2; ++nj) bF[nj] = rdfrag(B1, wn * 64 + nj * 16 + lr, q);
    __builtin_amdgcn_s_setprio(1);
#pragma unroll
    for (int mi = 0; mi < 8; ++mi)
#pragma unroll
      for (int nj = 0; nj < 2; ++nj)
        acc[mi][nj] = __builtin_amdgcn_mfma_f32_16x16x32_f16(aF[mi], bF[nj], acc[mi][nj], 0, 0, 0);
    __builtin_amdgcn_s_setprio(0);
    LGKM0();
    SBAR();

    // P3
    As(bf_ + 2, k2 + 32);
    SBAR();
#pragma unroll
    for (int nj = 0; nj < 2; ++nj) bF[nj] = rdfrag(B1, wn * 64 + (nj + 2) * 16 + lr, q);
    __builtin_amdgcn_s_setprio(1);
#pragma unroll
    for (int mi = 0; mi < 8; ++mi)
#pragma unroll
      for (int nj = 0; nj < 2; ++nj)
        acc[mi][nj + 2] = __builtin_amdgcn_mfma_f32_16x16x32_f16(aF[mi], bF[nj], acc[mi][nj + 2], 0, 0, 0);
    __builtin_amdgcn_s_setprio(0);
    LGKM0();
    SBAR();
  }

  // Epilogue: drain, scatter proj (+bias) into LDS, then paired gate combine.
  VMCNT(0);
  SBAR();
  _Float16* E = LDSA;  // 256x256 f16 row-major (interleaved nonlin/gate cols)
#pragma unroll
  for (int nj = 0; nj < 4; ++nj) {
    const int col = wn * 64 + nj * 16 + lr;
    const int gcol = n0 + col;
    const float bv = bias[((gcol & 1) << 9) + (gcol >> 1)];
#pragma unroll
    for (int mi = 0; mi < 8; ++mi)
#pragma unroll
      for (int g = 0; g < 4; ++g) {
        const int row = wm * 128 + mi * 16 + q * 4 + g;
        E[row * 256 + col] = (_Float16)(acc[mi][nj][g] + bv);
      }
  }
  LGKM0();
  SBAR();
  // 4096 iterations x (2 x 16B reads) = full 256x256 tile (pairs u,v).
#pragma unroll
  for (int j = 0; j < 8; ++j) {
    const int cid = j * 512 + tid;
    const int row = cid >> 4, pc = cid & 15;
    f16x8 u = *(const f16x8*)&E[row * 256 + pc * 16];
    f16x8 v = *(const f16x8*)&E[row * 256 + pc * 16 + 8];
    const int xrow = m0 + row;
    const int oc0 = (n0 >> 1) + pc * 8;
    f16x8 xv8 = *(const f16x8*)&x[(size_t)xrow * HD + oc0];
    f16x8 o8;
    float of[8];
#pragma unroll
    for (int e = 0; e < 8; ++e) {
      float nl = (e < 4) ? (float)u[2 * e]     : (float)v[2 * e - 8];
      float gz = (e < 4) ? (float)u[2 * e + 1] : (float)v[2 * e - 7];
      nl = nl > 0.f ? nl : 0.f;
      const float gt = 1.f / (1.f + __expf(-gz));
      const float o = gt * (float)xv8[e] + (1.f - gt) * nl;
      of[e] = o;
      o8[e] = (_Float16)o;
    }
    if (mode == 0) {
      *(f16x8*)&oh[(size_t)xrow * HD + oc0] = o8;
    } else {
      if (mode == 1) {
        const int bb = xrow >> 9, tt = xrow & (SQ - 1);
        *(f16x8*)&oh[((size_t)(bb * PROW + WID + tt)) * HD + oc0] = o8;
      }
      float* op = out32 + (size_t)xrow * (2 * HD) + dir * HD + oc0;
      *(float4*)op = make_float4(of[0], of[1], of[2], of[3]);
      *(float4*)(op + 4) = make_float4(of[4], of[5], of[6], of[7]);
    }
  }
}

// ---------------------------------------------------------------------------
extern "C" void kernel_launch(void* const* d_in, const int* in_sizes, int n_in,
                              void* d_out, int out_size, void* d_ws, size_t ws_size,
                              hipStream_t stream) {
  const float* inputs   = (const float*)d_in[0];
  // d_in[1] = mask (all ones, unused by reference math)
  const float* fwd_pads = (const float*)d_in[2];   // [3][4][512]
  const float* bwd_pads = (const float*)d_in[3];
  const float* fwd_W    = (const float*)d_in[4];   // [3][2560][512]
  const float* fwd_b    = (const float*)d_in[5];   // [3][512]
  const float* bwd_W    = (const float*)d_in[6];
  const float* bwd_b    = (const float*)d_in[7];
  const float* fwd_hw_W = (const float*)d_in[8];   // [3][2][512][1024]
  const float* fwd_hw_b = (const float*)d_in[9];   // [3][2][1024]
  const float* bwd_hw_W = (const float*)d_in[10];
  const float* bwd_hw_b = (const float*)d_in[11];
  float* out = (float*)d_out;

  char* p = (char*)d_ws;
  auto take = [&](size_t n) { char* r = p; p += (n + 255) & ~(size_t)255; return r; };

  _Float16* padF = (_Float16*)take((size_t)LAY * PSTR * 2);   // per-layer pad bufs
  _Float16* padB = (_Float16*)take((size_t)LAY * PSTR * 2);
  _Float16* tF   = (_Float16*)take((size_t)MR * HD * 2);
  _Float16* tB   = (_Float16*)take((size_t)MR * HD * 2);
  _Float16* uF   = (_Float16*)take((size_t)MR * HD * 2);
  _Float16* uB   = (_Float16*)take((size_t)MR * HD * 2);
  _Float16* WtcF = (_Float16*)take((size_t)LAY * HD * KIN * 2);
  _Float16* WtcB = (_Float16*)take((size_t)LAY * HD * KIN * 2);
  _Float16* WthF = (_Float16*)take((size_t)LAY * 2 * (2 * HD) * HD * 2);
  _Float16* WthB = (_Float16*)take((size_t)LAY * 2 * (2 * HD) * HD * 2);

  // Weight transpose+convert (fp32 -> fp16, [R][C] -> [C][R] per slice)
  transpose_w2<<<dim3(HD / 32, KIN / 32, 2 * LAY), dim3(32, 8), 0, stream>>>(
      fwd_W, bwd_W, WtcF, WtcB, KIN, HD, LAY, 0);
  transpose_w2<<<dim3((2 * HD) / 32, HD / 32, 2 * LAY * 2), dim3(32, 8), 0, stream>>>(
      fwd_hw_W, bwd_hw_W, WthF, WthB, HD, 2 * HD, LAY * 2, 1);

  // Layer-0 activations into layer-0 pad interiors; all border rows once
  init_interior<<<(NB * SQ * HD / 4) / 256, 256, 0, stream>>>((const float4*)inputs, padF, padB);
  fill_all_pads<<<(LAY * 2 * NB * WID * HD) / 256, 256, 0, stream>>>(fwd_pads, bwd_pads, padF, padB);

  for (int i = 0; i < LAY; ++i) {
    _Float16* pF = padF + (size_t)i * PSTR;
    _Float16* pB = padB + (size_t)i * PSTR;
    const int nx = (i + 1 < LAY) ? (i + 1) : 0;   // dummy for last layer (mode 2)
    _Float16* nF = padF + (size_t)nx * PSTR;
    _Float16* nB = padB + (size_t)nx * PSTR;

    conv_gemm<<<dim3(256), dim3(512), 0, stream>>>(
        pF, pB,
        WtcF + (size_t)i * HD * KIN, WtcB + (size_t)i * HD * KIN,
        fwd_b + (size_t)i * HD, bwd_b + (size_t)i * HD, tF, tB);
    hw_gemm<<<dim3(512), dim3(512), 0, stream>>>(
        tF, tB,
        WthF + (size_t)(i * 2 + 0) * (2 * HD) * HD, WthB + (size_t)(i * 2 + 0) * (2 * HD) * HD,
        fwd_hw_b + (size_t)(i * 2 + 0) * (2 * HD), bwd_hw_b + (size_t)(i * 2 + 0) * (2 * HD),
        uF, uB, nullptr, 0);
    hw_gemm<<<dim3(512), dim3(512), 0, stream>>>(
        uF, uB,
        WthF + (size_t)(i * 2 + 1) * (2 * HD) * HD, WthB + (size_t)(i * 2 + 1) * (2 * HD) * HD,
        fwd_hw_b + (size_t)(i * 2 + 1) * (2 * HD), bwd_hw_b + (size_t)(i * 2 + 1) * (2 * HD),
        nF, nB, out + (size_t)i * MR * (2 * HD), (i + 1 < LAY) ? 1 : 2);
  }
}